// Round 6
// baseline (2023.135 us; speedup 1.0000x reference)
//
#include <hip/hip_runtime.h>
#include <hip/hip_bf16.h>
#include <math.h>

#define NROWS 131072
#define ACT_D 12
#define COND_D 256
#define KEMB 256
#define EDIM 16
#define H1D 512
#define H2D 256
#define NB 16384

typedef __attribute__((ext_vector_type(8))) _Float16 half8;
typedef __attribute__((ext_vector_type(4))) float floatx4;
typedef unsigned short ushort_t;

#define LO_SCALE 4096.0f
#define INV_LO_SCALE 2.44140625e-4f

// ---------------------------------------------------------------------------
// Memory plan (unchanged).
// d_ws:
//   counts @ 0        (256 ints)
//   stats  @ 256      (1536 ints)
//   P2     @ 1792     : h2hi/h2lo -> d1hi/d1lo (f16 pairs)
//   P1     @ 33556224 : h1hi/h1lo -> distT(fp32) -> d2hi/d2lo
// d_out outRec region hosts converted transposed hi/lo-split weights until D2.
//
// Numerics: fp32 a = hi + lo*2^-12, hi=f16(a), lo=f16((a-hi)*4096).
// A@B = AhiBhi (accH) + (AhiBlo'+Alo'Bhi) (accX), out = accH + accX*2^-12.
//
// GEMM v6 (this round): FULLY DIRECT, BARRIER-FREE. R5 counters: MfmaUtil
// 18.3% == MFMA-cy/window exactly; A-through-LDS (each wave re-reads the whole
// 8KB A tile, 4x redundancy) is ~half the 665-cy window; __syncthreads drains
// the just-issued B loads every step. Fix: 2x2 wave split (32 rows x 64 cols
// per wave) -> A fragment = 16B contiguous per lane in [M,Kp] -> per-lane
// global_load_dwordx4 for BOTH A and B. No LDS, no barriers, no DMA: 12-16
// independent wave-streams/CU; A prefetched one K-step ahead into named next
// regs (rule #20: no runtime-indexed reg arrays). CONCAT path: raw fp32
// prefetch + in-register splitf after compute. MFMA fragment values and
// per-acc accumulation order identical to v5 -> bitwise-same outputs.
// ---------------------------------------------------------------------------

__global__ void init_kernel(int* counts, float* outScal) {
    int t = threadIdx.x;
    counts[t] = 0;
    if (t < 5) outScal[t] = 0.0f;
}

__device__ inline ushort_t f16bits(_Float16 h) { return __builtin_bit_cast(ushort_t, h); }
__device__ inline float f16pair(ushort_t a, ushort_t b) {
    return (float)__builtin_bit_cast(_Float16, a)
         + (float)__builtin_bit_cast(_Float16, b) * INV_LO_SCALE;
}
__device__ inline void splitf(float v, ushort_t& hi, ushort_t& lo) {
    _Float16 h = (_Float16)v;
    _Float16 l = (_Float16)((v - (float)h) * LO_SCALE);
    hi = f16bits(h); lo = f16bits(l);
}

// ---------------------------------------------------------------------------
// Weight conversion: W [K,N] fp32 -> Whi/Wlo [N,Kp] f16 (transposed, padded).
// ---------------------------------------------------------------------------
__global__ __launch_bounds__(256)
void convw_kernel(const float* __restrict__ W, ushort_t* __restrict__ Whi,
                  ushort_t* __restrict__ Wlo, int K, int N, int Kp)
{
    int n = blockIdx.x;
    int k = blockIdx.y * 256 + threadIdx.x;
    if (k >= Kp) return;
    float v = (k < K) ? W[(long)k * N + n] : 0.0f;
    ushort_t h, l; splitf(v, h, l);
    Whi[(long)n * Kp + k] = h;
    Wlo[(long)n * Kp + k] = l;
}

// ---------------------------------------------------------------------------
// f16x3 (scaled-lo) MFMA GEMM + bias + ELU.  C = elu(A @ W + b).
// BM=64, BN=128, BK=32, 256 thr; wave w: wr=w&1 (row half, 32 rows),
// wc=w>>1 (col half, 64 cols).  A and B both per-lane global_load_dwordx4
// (no LDS, no barriers).
// MFMA mappings (m89/m120-verified): A[m=lane&15][k=quad*8+j],
// B[k=quad*8+j][n=lane&15], C col=lane&15 row=quad*4+reg.
// ---------------------------------------------------------------------------
template<int CONCAT>
__global__ __launch_bounds__(256, 3)
void gemm_f16x3_kernel(const void* A0v, const void* A1v,
                       const ushort_t* __restrict__ Bhi, const ushort_t* __restrict__ Blo,
                       const float* __restrict__ bias,
                       ushort_t* __restrict__ Chi, ushort_t* __restrict__ Clo,
                       int Nw, int Kp, int Kvalid)
{
    const int tid = threadIdx.x;
    const int w = tid >> 6, l = tid & 63;
    const int quad = l >> 4, lr = l & 15;
    const int wr = w & 1, wc = w >> 1;
    const long rowBase = (long)blockIdx.x * 64;
    const int colBase = blockIdx.y * 128;

    floatx4 accH[2][4], accX[2][4];
#pragma unroll
    for (int i = 0; i < 2; ++i)
#pragma unroll
        for (int j = 0; j < 4; ++j) { accH[i][j] = (floatx4)(0.0f); accX[i][j] = (floatx4)(0.0f); }

    // ---- B fragment base pointers (per lane, direct from cache) ----
    const long bcol = colBase + wc * 64 + lr;
    const ushort_t* pB0h = Bhi + (bcol +  0) * (long)Kp + quad * 8;
    const ushort_t* pB1h = Bhi + (bcol + 16) * (long)Kp + quad * 8;
    const ushort_t* pB2h = Bhi + (bcol + 32) * (long)Kp + quad * 8;
    const ushort_t* pB3h = Bhi + (bcol + 48) * (long)Kp + quad * 8;
    const ushort_t* pB0l = Blo + (bcol +  0) * (long)Kp + quad * 8;
    const ushort_t* pB1l = Blo + (bcol + 16) * (long)Kp + quad * 8;
    const ushort_t* pB2l = Blo + (bcol + 32) * (long)Kp + quad * 8;
    const ushort_t* pB3l = Blo + (bcol + 48) * (long)Kp + quad * 8;

    uint4 b0h, b1h, b2h, b3h, b0l, b1l, b2l, b3l;     // current-tile B (named)
    auto loadB = [&](int k0) {
        b0h = *(const uint4*)(pB0h + k0);
        b1h = *(const uint4*)(pB1h + k0);
        b2h = *(const uint4*)(pB2h + k0);
        b3h = *(const uint4*)(pB3h + k0);
        b0l = *(const uint4*)(pB0l + k0);
        b1l = *(const uint4*)(pB1l + k0);
        b2l = *(const uint4*)(pB2l + k0);
        b3l = *(const uint4*)(pB3l + k0);
    };

    // ---- A: current + next named regs ----
    const long arow0 = rowBase + wr * 32 + lr;        // im=0 row; im=1 is +16
    uint4 a0h, a1h, a0l, a1l;                         // current tile
    uint4 n0h, n1h, n0l, n1l;                         // prefetched next (CONCAT==0)
    float v0[8], v1[8];                               // prefetched raw fp32 (CONCAT!=0)

    // CONCAT==0: A is pre-split f16 hi/lo, [M,Kp]
    const ushort_t* pA0h = (const ushort_t*)A0v + arow0 * Kp + quad * 8;
    const ushort_t* pA1h = pA0h + 16 * (long)Kp;
    const ushort_t* pA0l = (const ushort_t*)A1v + arow0 * Kp + quad * 8;
    const ushort_t* pA1l = pA0l + 16 * (long)Kp;
    auto loadAnext = [&](int k0) {
        n0h = *(const uint4*)(pA0h + k0);
        n1h = *(const uint4*)(pA1h + k0);
        n0l = *(const uint4*)(pA0l + k0);
        n1l = *(const uint4*)(pA1l + k0);
    };

    // CONCAT!=0: raw fp32 concat loads (per-lane k-range; divergent only at
    // the concat seam / K tail), conversion deferred until after compute.
    const float* A1p = (const float*)A0v;
    const float* A2p = (const float*)A1v;
    auto aloadRow = [&](float* v, long row, int k0) {
        const int kk = k0 + quad * 8;                 // per-lane
        if (kk >= CONCAT && kk + 8 <= Kvalid) {
            const float* p = A2p + row * COND_D + (kk - CONCAT);
            *(float4*)&v[0] = *(const float4*)p;
            *(float4*)&v[4] = *(const float4*)(p + 4);
        } else if (kk + 8 <= CONCAT) {
            const float* p = A1p + row * CONCAT + kk;
            *(float4*)&v[0] = *(const float4*)p;
            *(float4*)&v[4] = *(const float4*)(p + 4);
        } else {
#pragma unroll
            for (int i = 0; i < 8; ++i) {
                int k = kk + i;
                v[i] = (k < CONCAT) ? A1p[row * CONCAT + k]
                     : (k < Kvalid) ? A2p[row * COND_D + (k - CONCAT)] : 0.0f;
            }
        }
    };
    auto convertRow = [&](const float* v, uint4& h4, uint4& l4) {
        uint hh[4], ll[4];
#pragma unroll
        for (int i = 0; i < 4; ++i) {
            ushort_t h0, l0, h1, l1;
            splitf(v[2 * i], h0, l0);
            splitf(v[2 * i + 1], h1, l1);
            hh[i] = (uint)h0 | ((uint)h1 << 16);
            ll[i] = (uint)l0 | ((uint)l1 << 16);
        }
        h4 = *(uint4*)hh; l4 = *(uint4*)ll;
    };

    // ---- 24 MFMAs on current A/B regs (per-acc order identical to v5) ----
    auto compute = [&]() {
        half8 A0h = __builtin_bit_cast(half8, a0h), A0l = __builtin_bit_cast(half8, a0l);
        half8 A1h = __builtin_bit_cast(half8, a1h), A1l = __builtin_bit_cast(half8, a1l);
        half8 B0h = __builtin_bit_cast(half8, b0h), B0l = __builtin_bit_cast(half8, b0l);
        half8 B1h = __builtin_bit_cast(half8, b1h), B1l = __builtin_bit_cast(half8, b1l);
        half8 B2h = __builtin_bit_cast(half8, b2h), B2l = __builtin_bit_cast(half8, b2l);
        half8 B3h = __builtin_bit_cast(half8, b3h), B3l = __builtin_bit_cast(half8, b3l);
        accH[0][0] = __builtin_amdgcn_mfma_f32_16x16x32_f16(A0h, B0h, accH[0][0], 0, 0, 0);
        accX[0][0] = __builtin_amdgcn_mfma_f32_16x16x32_f16(A0h, B0l, accX[0][0], 0, 0, 0);
        accX[0][0] = __builtin_amdgcn_mfma_f32_16x16x32_f16(A0l, B0h, accX[0][0], 0, 0, 0);
        accH[0][1] = __builtin_amdgcn_mfma_f32_16x16x32_f16(A0h, B1h, accH[0][1], 0, 0, 0);
        accX[0][1] = __builtin_amdgcn_mfma_f32_16x16x32_f16(A0h, B1l, accX[0][1], 0, 0, 0);
        accX[0][1] = __builtin_amdgcn_mfma_f32_16x16x32_f16(A0l, B1h, accX[0][1], 0, 0, 0);
        accH[0][2] = __builtin_amdgcn_mfma_f32_16x16x32_f16(A0h, B2h, accH[0][2], 0, 0, 0);
        accX[0][2] = __builtin_amdgcn_mfma_f32_16x16x32_f16(A0h, B2l, accX[0][2], 0, 0, 0);
        accX[0][2] = __builtin_amdgcn_mfma_f32_16x16x32_f16(A0l, B2h, accX[0][2], 0, 0, 0);
        accH[0][3] = __builtin_amdgcn_mfma_f32_16x16x32_f16(A0h, B3h, accH[0][3], 0, 0, 0);
        accX[0][3] = __builtin_amdgcn_mfma_f32_16x16x32_f16(A0h, B3l, accX[0][3], 0, 0, 0);
        accX[0][3] = __builtin_amdgcn_mfma_f32_16x16x32_f16(A0l, B3h, accX[0][3], 0, 0, 0);
        accH[1][0] = __builtin_amdgcn_mfma_f32_16x16x32_f16(A1h, B0h, accH[1][0], 0, 0, 0);
        accX[1][0] = __builtin_amdgcn_mfma_f32_16x16x32_f16(A1h, B0l, accX[1][0], 0, 0, 0);
        accX[1][0] = __builtin_amdgcn_mfma_f32_16x16x32_f16(A1l, B0h, accX[1][0], 0, 0, 0);
        accH[1][1] = __builtin_amdgcn_mfma_f32_16x16x32_f16(A1h, B1h, accH[1][1], 0, 0, 0);
        accX[1][1] = __builtin_amdgcn_mfma_f32_16x16x32_f16(A1h, B1l, accX[1][1], 0, 0, 0);
        accX[1][1] = __builtin_amdgcn_mfma_f32_16x16x32_f16(A1l, B1h, accX[1][1], 0, 0, 0);
        accH[1][2] = __builtin_amdgcn_mfma_f32_16x16x32_f16(A1h, B2h, accH[1][2], 0, 0, 0);
        accX[1][2] = __builtin_amdgcn_mfma_f32_16x16x32_f16(A1h, B2l, accX[1][2], 0, 0, 0);
        accX[1][2] = __builtin_amdgcn_mfma_f32_16x16x32_f16(A1l, B2h, accX[1][2], 0, 0, 0);
        accH[1][3] = __builtin_amdgcn_mfma_f32_16x16x32_f16(A1h, B3h, accH[1][3], 0, 0, 0);
        accX[1][3] = __builtin_amdgcn_mfma_f32_16x16x32_f16(A1h, B3l, accX[1][3], 0, 0, 0);
        accX[1][3] = __builtin_amdgcn_mfma_f32_16x16x32_f16(A1l, B3h, accX[1][3], 0, 0, 0);
    };

    const int kTiles = Kp / 32;

    if constexpr (CONCAT == 0) {
        // prologue: tile 0 into current regs
        n0h = *(const uint4*)(pA0h); n1h = *(const uint4*)(pA1h);
        n0l = *(const uint4*)(pA0l); n1l = *(const uint4*)(pA1l);
        loadB(0);
        a0h = n0h; a1h = n1h; a0l = n0l; a1l = n1l;
        for (int t = 0; t < kTiles; ++t) {
            const bool hn = (t + 1 < kTiles);
            const int k0n = (t + 1) * 32;
            if (hn) loadAnext(k0n);          // A[t+1] in flight during compute
            compute();                        // waits only on cur A/B
            if (hn) {
                loadB(k0n);                   // B[t+1] (L2-hot) after last B[t] use
                a0h = n0h; a1h = n1h; a0l = n0l; a1l = n1l;
            }
        }
    } else {
        // prologue: raw tile 0, convert immediately
        aloadRow(v0, arow0, 0);
        aloadRow(v1, arow0 + 16, 0);
        loadB(0);
        convertRow(v0, a0h, a0l);
        convertRow(v1, a1h, a1l);
        for (int t = 0; t < kTiles; ++t) {
            const bool hn = (t + 1 < kTiles);
            const int k0n = (t + 1) * 32;
            if (hn) {
                aloadRow(v0, arow0, k0n);     // raw A[t+1] in flight during compute
                aloadRow(v1, arow0 + 16, k0n);
            }
            compute();
            if (hn) {
                loadB(k0n);
                convertRow(v0, a0h, a0l);     // loads landed under compute
                convertRow(v1, a1h, a1l);
            }
        }
    }

    // ---- epilogue: combine, bias, ELU, hi/lo split store ----
    float bv[4];
#pragma unroll
    for (int jn = 0; jn < 4; ++jn) bv[jn] = bias[colBase + wc * 64 + jn * 16 + lr];
#pragma unroll
    for (int im = 0; im < 2; ++im) {
#pragma unroll
        for (int jn = 0; jn < 4; ++jn) {
            int n = colBase + wc * 64 + jn * 16 + lr;
#pragma unroll
            for (int rr = 0; rr < 4; ++rr) {
                long m = rowBase + wr * 32 + im * 16 + quad * 4 + rr;
                float x = accH[im][jn][rr] + accX[im][jn][rr] * INV_LO_SCALE + bv[jn];
                x = x > 0.0f ? x : (expf(x) - 1.0f);
                ushort_t h, lo; splitf(x, h, lo);
                long idx = m * Nw + n;
                Chi[idx] = h;
                Clo[idx] = lo;
            }
        }
    }
}

// ---------------------------------------------------------------------------
// K3: z = h2@W3+b3 (fp32, h2 = hi + lo*2^-12), normalize, argmax,
// quantized -> d_out, q-latent partial, counts, distT (transposed) write.
// ---------------------------------------------------------------------------
__global__ __launch_bounds__(256)
void quantize_kernel(const ushort_t* __restrict__ h2hi, const ushort_t* __restrict__ h2lo,
                     const float* __restrict__ W3,
                     const float* __restrict__ b3, const float* __restrict__ emb,
                     float* __restrict__ distT, float* __restrict__ outQ,
                     float* __restrict__ outIdx, int* __restrict__ counts,
                     float* __restrict__ qsum)
{
    __shared__ float h2t[16 * 260];
    __shared__ float w3t[16 * 260];
    __shared__ float nwt[256 * 20];
    __shared__ float zt[16 * 17];
    __shared__ float dt[16 * 257];
    __shared__ int   lcnt[256];
    __shared__ float swred[4];

    int t = threadIdx.x;
    long rowBase = (long)blockIdx.x * 16;

    for (int it = 0; it < 16; ++it) {
        long idx = (rowBase + it) * 256 + t;
        h2t[it * 260 + t] = f16pair(h2hi[idx], h2lo[idx]);
    }
    for (int it = 0; it < 16; ++it) {
        int flat = it * 256 + t;
        int j = flat >> 4, c = flat & 15;
        w3t[c * 260 + j] = W3[flat];
    }
    {
        float e0[16]; float ss = 0.f;
#pragma unroll
        for (int i = 0; i < 16; ++i) { e0[i] = emb[t * 16 + i]; ss += e0[i] * e0[i]; }
        float inv = 1.0f / fmaxf(sqrtf(ss), 1e-12f);
#pragma unroll
        for (int i = 0; i < 16; ++i) nwt[t * 20 + i] = e0[i] * inv;
    }
    lcnt[t] = 0;
    __syncthreads();

    int r = t >> 4, c = t & 15;
    float zacc = b3[c];
    for (int j4 = 0; j4 < 64; ++j4) {
        float4 h = *(const float4*)&h2t[r * 260 + j4 * 4];
        float4 w = *(const float4*)&w3t[c * 260 + j4 * 4];
        zacc += h.x * w.x + h.y * w.y + h.z * w.z + h.w * w.w;
    }
    float ss = zacc * zacc;
#pragma unroll
    for (int m = 1; m < 16; m <<= 1) ss += __shfl_xor(ss, m, 64);
    zt[r * 17 + c] = zacc / fmaxf(sqrtf(ss), 1e-12f);
    __syncthreads();

    float zr[16];
#pragma unroll
    for (int e = 0; e < 16; ++e) zr[e] = zt[r * 17 + e];
    float best = -1e30f; int bidx = 0;
    for (int cc = 0; cc < 16; ++cc) {
        int col = cc * 16 + c;
        float d = 0.f;
#pragma unroll
        for (int e4 = 0; e4 < 4; ++e4) {
            float4 wv = *(const float4*)&nwt[col * 20 + e4 * 4];
            d += zr[e4 * 4 + 0] * wv.x + zr[e4 * 4 + 1] * wv.y
               + zr[e4 * 4 + 2] * wv.z + zr[e4 * 4 + 3] * wv.w;
        }
        dt[r * 257 + col] = d;
        if (d > best || (d == best && col < bidx)) { best = d; bidx = col; }
    }
#pragma unroll
    for (int m = 1; m < 16; m <<= 1) {
        float ov = __shfl_xor(best, m, 64);
        int   oi = __shfl_xor(bidx, m, 64);
        if (ov > best || (ov == best && oi < bidx)) { best = ov; bidx = oi; }
    }

    float q = emb[bidx * 16 + c];
    outQ[(rowBase + r) * 16 + c] = q;
    float df = q - zacc;
    float part = df * df;
#pragma unroll
    for (int m = 1; m < 64; m <<= 1) part += __shfl_xor(part, m, 64);
    if ((t & 63) == 0) swred[t >> 6] = part;
    if (c == 0) {
        outIdx[rowBase + r] = (float)bidx;
        atomicAdd(&lcnt[bidx], 1);
    }
    __syncthreads();
    if (t == 0) atomicAdd(qsum, swred[0] + swred[1] + swred[2] + swred[3]);
    if (lcnt[t] > 0) atomicAdd(&counts[t], lcnt[t]);

    int rr = t & 15, cg = t >> 4;
    for (int i = 0; i < 16; ++i) {
        int col = i * 16 + cg;
        distT[(long)col * NROWS + rowBase + rr] = dt[rr * 257 + col];
    }
}

// ---------------------------------------------------------------------------
// SelA: per-column histogram; median bin and top-512 threshold bin.
// ---------------------------------------------------------------------------
__global__ __launch_bounds__(1024)
void selA_kernel(const float* __restrict__ distT, int* __restrict__ stats)
{
    __shared__ int hist[NB];
    __shared__ int part[1024];
    int t = threadIdx.x, c = blockIdx.x;
    for (int i = t; i < NB; i += 1024) hist[i] = 0;
    __syncthreads();
    const float* col = distT + (long)c * NROWS;
    for (int i = t; i < NROWS; i += 1024) {
        float v = col[i];
        int b = (int)((v + 1.0f) * (NB * 0.5f));
        b = min(max(b, 0), NB - 1);
        atomicAdd(&hist[b], 1);
    }
    __syncthreads();
    const int CH = NB / 1024;
    int s = 0;
    for (int i = 0; i < CH; ++i) s += hist[t * CH + i];
    part[t] = s;
    __syncthreads();
    if (t == 0) {
        int target = NROWS / 2;
        int cum = 0; int chunk = 0;
        while (cum + part[chunk] < target) { cum += part[chunk]; ++chunk; }
        int b = chunk * CH;
        while (cum + hist[b] < target) { cum += hist[b]; ++b; }
        int medBin = b, needLow = target - cum, cntMed = hist[b];
        int cumA = 0; chunk = 1023;
        while (cumA + part[chunk] < 512) { cumA += part[chunk]; --chunk; }
        b = chunk * CH + CH - 1;
        while (cumA + hist[b] < 512) { cumA += hist[b]; --b; }
        int topBin = b, needTop = 512 - cumA, cntTop = hist[b];
        int* st = stats + c * 6;
        st[0] = medBin; st[1] = needLow; st[2] = cntMed;
        st[3] = topBin; st[4] = needTop; st[5] = cntTop;
    }
}

// ---------------------------------------------------------------------------
// SelB: re-scan column; top-512 mean and logsumexp over bottom half.
// ---------------------------------------------------------------------------
__global__ __launch_bounds__(1024)
void selB_kernel(const float* __restrict__ distT, const int* __restrict__ stats,
                 float* __restrict__ contra_sum)
{
    __shared__ float red[64];
    int t = threadIdx.x, c = blockIdx.x;
    const int* st = stats + c * 6;
    int medBin = st[0], needLow = st[1], cntMed = st[2];
    int topBin = st[3], needTop = st[4], cntTop = st[5];
    const float binw = 2.0f / NB;
    float mUp = -1.0f + (medBin + 1) * binw;
    const float INVT = 1.0f / 0.07f;
    const float* col = distT + (long)c * NROWS;
    float topS = 0.f, tbS = 0.f, lowS = 0.f, mbS = 0.f;
    for (int i = t; i < NROWS; i += 1024) {
        float v = col[i];
        int b = (int)((v + 1.0f) * (NB * 0.5f));
        b = min(max(b, 0), NB - 1);
        if (b > topBin)       topS += v;
        else if (b == topBin) tbS += v;
        if (b < medBin)       lowS += expf((v - mUp) * INVT);
        else if (b == medBin) mbS  += expf((v - mUp) * INVT);
    }
#pragma unroll
    for (int m = 1; m < 64; m <<= 1) {
        topS += __shfl_xor(topS, m, 64);
        tbS  += __shfl_xor(tbS, m, 64);
        lowS += __shfl_xor(lowS, m, 64);
        mbS  += __shfl_xor(mbS, m, 64);
    }
    if ((t & 63) == 0) {
        int wv = t >> 6;
        red[wv * 4 + 0] = topS; red[wv * 4 + 1] = tbS;
        red[wv * 4 + 2] = lowS; red[wv * 4 + 3] = mbS;
    }
    __syncthreads();
    if (t == 0) {
        float T0 = 0, T1 = 0, T2 = 0, T3 = 0;
        for (int wv = 0; wv < 16; ++wv) {
            T0 += red[wv * 4 + 0]; T1 += red[wv * 4 + 1];
            T2 += red[wv * 4 + 2]; T3 += red[wv * 4 + 3];
        }
        float dis_pos = (T0 + needTop * (T1 / cntTop)) * (1.0f / 512.0f);
        float S = T2 + needLow * (T3 / cntMed);
        float colContra = log1pf(S * expf((mUp - dis_pos) * INVT));
        atomicAdd(contra_sum, colContra);
    }
}

// ---------------------------------------------------------------------------
// D3: reconstructed = d2 @ dec_w3 + b (d2 = hi + lo*2^-12), + recon loss.
// ---------------------------------------------------------------------------
__global__ __launch_bounds__(256)
void dec3_kernel(const ushort_t* __restrict__ d2hi, const ushort_t* __restrict__ d2lo,
                 const float* __restrict__ W,
                 const float* __restrict__ bias, const float* __restrict__ actions,
                 float* __restrict__ rec, float* __restrict__ recon_sum)
{
    __shared__ float dtile[16 * 516];
    __shared__ float wt[512 * 12];
    __shared__ float red2[4];
    int t = threadIdx.x;
    long rowBase = (long)blockIdx.x * 16;
    for (int it = 0; it < 24; ++it) wt[it * 256 + t] = W[it * 256 + t];
    for (int it = 0; it < 32; ++it) {
        int flat = it * 256 + t;
        int r = flat >> 9, k = flat & 511;
        long idx = (rowBase + r) * 512 + k;
        dtile[r * 516 + k] = f16pair(d2hi[idx], d2lo[idx]);
    }
    __syncthreads();
    float part = 0.f;
    if (t < 192) {
        int r = t / 12, cc = t % 12;
        float acc = bias[cc];
        for (int k4 = 0; k4 < 128; ++k4) {
            float4 h = *(const float4*)&dtile[r * 516 + k4 * 4];
            acc += h.x * wt[(k4 * 4 + 0) * 12 + cc] + h.y * wt[(k4 * 4 + 1) * 12 + cc]
                 + h.z * wt[(k4 * 4 + 2) * 12 + cc] + h.w * wt[(k4 * 4 + 3) * 12 + cc];
        }
        rec[(rowBase + r) * 12 + cc] = acc;
        float df = acc - actions[(rowBase + r) * 12 + cc];
        part = df * df;
    }
#pragma unroll
    for (int m = 1; m < 64; m <<= 1) part += __shfl_xor(part, m, 64);
    if ((t & 63) == 0) red2[t >> 6] = part;
    __syncthreads();
    if (t == 0) atomicAdd(recon_sum, red2[0] + red2[1] + red2[2] + red2[3]);
}

// ---------------------------------------------------------------------------
// finalize: perplexity from counts + scalar outputs.
// ---------------------------------------------------------------------------
__global__ void finalize_kernel(const int* __restrict__ counts, float* __restrict__ outScal)
{
    __shared__ float red[4];
    int t = threadIdx.x;
    float p = counts[t] * (1.0f / NROWS);
    float term = p * logf(p + 1e-10f);
#pragma unroll
    for (int m = 1; m < 64; m <<= 1) term += __shfl_xor(term, m, 64);
    if ((t & 63) == 0) red[t >> 6] = term;
    __syncthreads();
    if (t == 0) {
        float hsum = red[0] + red[1] + red[2] + red[3];
        float qsum = outScal[0], contra = outScal[2], recon = outScal[4];
        float ql = qsum * (1.0f / (NROWS * 16.0f));
        outScal[0] = ql;
        outScal[1] = 0.25f * ql;
        outScal[2] = contra * (1.0f / 256.0f);
        outScal[3] = expf(-hsum);
        outScal[4] = recon * (1.0f / (NROWS * 12.0f));
    }
}

extern "C" void kernel_launch(void* const* d_in, const int* in_sizes, int n_in,
                              void* d_out, int out_size, void* d_ws, size_t ws_size,
                              hipStream_t stream)
{
    const float* actions    = (const float*)d_in[0];
    const float* conditions = (const float*)d_in[1];
    const float* enc_w1 = (const float*)d_in[2];
    const float* enc_b1 = (const float*)d_in[3];
    const float* enc_w2 = (const float*)d_in[4];
    const float* enc_b2 = (const float*)d_in[5];
    const float* enc_w3 = (const float*)d_in[6];
    const float* enc_b3 = (const float*)d_in[7];
    const float* dec_w1 = (const float*)d_in[8];
    const float* dec_b1 = (const float*)d_in[9];
    const float* dec_w2 = (const float*)d_in[10];
    const float* dec_b2 = (const float*)d_in[11];
    const float* dec_w3 = (const float*)d_in[12];
    const float* dec_b3 = (const float*)d_in[13];
    const float* emb    = (const float*)d_in[14];

    float* out     = (float*)d_out;
    float* outRec  = out;
    float* outQ    = out + (long)NROWS * 12;
    float* outIdx  = out + (long)NROWS * 28;
    float* outScal = out + (long)NROWS * 29;

    // converted weights live in the (dead-until-dec3) outRec region
    ushort_t* wb    = (ushort_t*)d_out;
    ushort_t* w1hi  = wb;            ushort_t* w1lo  = wb + 147456;
    ushort_t* w2hi  = wb + 294912;   ushort_t* w2lo  = wb + 425984;
    ushort_t* wd1hi = wb + 557056;   ushort_t* wd1lo = wb + 630784;
    ushort_t* wd2hi = wb + 704512;   ushort_t* wd2lo = wb + 835584;

    float* ws = (float*)d_ws;
    int* counts = (int*)ws;
    int* stats  = (int*)(ws + 256);
    ushort_t* h2hi = (ushort_t*)(ws + 1792);
    ushort_t* h2lo = (ushort_t*)(ws + 16779008);
    ushort_t* d1hi = h2hi;
    ushort_t* d1lo = h2lo;
    float*    P1   = ws + 33556224;
    ushort_t* h1hi = (ushort_t*)P1;
    ushort_t* h1lo = (ushort_t*)(ws + 67110656);
    float*    distT = P1;
    ushort_t* d2hi = h1hi;
    ushort_t* d2lo = h1lo;

    hipLaunchKernelGGL(init_kernel, dim3(1), dim3(256), 0, stream, counts, outScal);
    hipLaunchKernelGGL(convw_kernel, dim3(512, 2), dim3(256), 0, stream, enc_w1, w1hi, w1lo, 268, 512, 288);
    hipLaunchKernelGGL(convw_kernel, dim3(256, 2), dim3(256), 0, stream, enc_w2, w2hi, w2lo, 512, 256, 512);
    hipLaunchKernelGGL(convw_kernel, dim3(256, 2), dim3(256), 0, stream, dec_w1, wd1hi, wd1lo, 272, 256, 288);
    hipLaunchKernelGGL(convw_kernel, dim3(512, 1), dim3(256), 0, stream, dec_w2, wd2hi, wd2lo, 256, 512, 256);
    // E1: h1 = elu(concat(actions,conditions) @ W1 + b1)
    hipLaunchKernelGGL((gemm_f16x3_kernel<ACT_D>), dim3(2048, 4), dim3(256), 0, stream,
                       (const void*)actions, (const void*)conditions, w1hi, w1lo, enc_b1,
                       h1hi, h1lo, H1D, 288, 268);
    // E2: h2 = elu(h1 @ W2 + b2)
    hipLaunchKernelGGL((gemm_f16x3_kernel<0>), dim3(2048, 2), dim3(256), 0, stream,
                       (const void*)h1hi, (const void*)h1lo, w2hi, w2lo, enc_b2,
                       h2hi, h2lo, H2D, 512, 512);
    // K3: z, normalize, argmax, quantized, counts, q-latent, distT
    hipLaunchKernelGGL(quantize_kernel, dim3(8192), dim3(256), 0, stream,
                       h2hi, h2lo, enc_w3, enc_b3, emb, distT, outQ, outIdx, counts, &outScal[0]);
    hipLaunchKernelGGL(selA_kernel, dim3(256), dim3(1024), 0, stream, distT, stats);
    hipLaunchKernelGGL(selB_kernel, dim3(256), dim3(1024), 0, stream, distT, stats, &outScal[2]);
    // D1: d1 = elu(concat(quantized,conditions) @ Wd1 + b1)
    hipLaunchKernelGGL((gemm_f16x3_kernel<EDIM>), dim3(2048, 2), dim3(256), 0, stream,
                       (const void*)outQ, (const void*)conditions, wd1hi, wd1lo, dec_b1,
                       d1hi, d1lo, H2D, 288, 272);
    // D2: d2 = elu(d1 @ Wd2 + b2)
    hipLaunchKernelGGL((gemm_f16x3_kernel<0>), dim3(2048, 4), dim3(256), 0, stream,
                       (const void*)d1hi, (const void*)d1lo, wd2hi, wd2lo, dec_b2,
                       d2hi, d2lo, H1D, 256, 256);
    // D3: reconstructed + loss
    hipLaunchKernelGGL(dec3_kernel, dim3(8192), dim3(256), 0, stream,
                       d2hi, d2lo, dec_w3, dec_b3, actions, outRec, &outScal[4]);
    hipLaunchKernelGGL(finalize_kernel, dim3(1), dim3(256), 0, stream, counts, outScal);
}

// Round 7
// 1523.781 us; speedup vs baseline: 1.3277x; 1.3277x over previous
//
#include <hip/hip_runtime.h>
#include <hip/hip_bf16.h>
#include <math.h>

#define NROWS 131072
#define ACT_D 12
#define COND_D 256
#define KEMB 256
#define EDIM 16
#define H1D 512
#define H2D 256
#define NB 16384

typedef __attribute__((ext_vector_type(8))) _Float16 half8;
typedef __attribute__((ext_vector_type(4))) float floatx4;
typedef unsigned short ushort_t;

#define LO_SCALE 4096.0f
#define INV_LO_SCALE 2.44140625e-4f

// ---------------------------------------------------------------------------
// Memory plan (unchanged).
// d_ws:
//   counts @ 0        (256 ints)
//   stats  @ 256      (1536 ints)
//   P2     @ 1792     : h2hi/h2lo -> d1hi/d1lo (f16 pairs)
//   P1     @ 33556224 : h1hi/h1lo -> distT(fp32) -> d2hi/d2lo
// d_out outRec region hosts converted transposed hi/lo-split weights until D2.
//
// Numerics: fp32 a = hi + lo*2^-12, hi=f16(a), lo=f16((a-hi)*4096).
// A@B = AhiBhi (accH) + (AhiBlo'+Alo'Bhi) (accX), out = accH + accX*2^-12.
//
// GEMM v7 (this round) = v5 (best measured: 271us/GEMM, A via LDS-DMA +
// B direct from L2, ports balanced) + ONE fix: B-register DOUBLE-BUFFER.
// v5's loop issued loadB(next) immediately before __syncthreads -> the
// barrier's vmcnt(0) drain exposed full L2 latency every K-step (~43% idle,
// busy-sum 57%). Now next-B loads into separate named regs BEFORE compute,
// so the barrier drain finds them already landed (whole MFMA phase to cover
// latency). v6's lesson kept: do NOT push A through TCP too (48KB/step on one
// port regressed 1.6x); A stays on the LDS path, B on the TCP path.
// ---------------------------------------------------------------------------

__global__ void init_kernel(int* counts, float* outScal) {
    int t = threadIdx.x;
    counts[t] = 0;
    if (t < 5) outScal[t] = 0.0f;
}

__device__ inline ushort_t f16bits(_Float16 h) { return __builtin_bit_cast(ushort_t, h); }
__device__ inline float f16pair(ushort_t a, ushort_t b) {
    return (float)__builtin_bit_cast(_Float16, a)
         + (float)__builtin_bit_cast(_Float16, b) * INV_LO_SCALE;
}
__device__ inline void splitf(float v, ushort_t& hi, ushort_t& lo) {
    _Float16 h = (_Float16)v;
    _Float16 l = (_Float16)((v - (float)h) * LO_SCALE);
    hi = f16bits(h); lo = f16bits(l);
}

__device__ inline void gload_lds16(const void* g, void* lds) {
    __builtin_amdgcn_global_load_lds((const __attribute__((address_space(1))) void*)g,
                                     (__attribute__((address_space(3))) void*)lds, 16, 0, 0);
}

// ---------------------------------------------------------------------------
// Weight conversion: W [K,N] fp32 -> Whi/Wlo [N,Kp] f16 (transposed, padded).
// ---------------------------------------------------------------------------
__global__ __launch_bounds__(256)
void convw_kernel(const float* __restrict__ W, ushort_t* __restrict__ Whi,
                  ushort_t* __restrict__ Wlo, int K, int N, int Kp)
{
    int n = blockIdx.x;
    int k = blockIdx.y * 256 + threadIdx.x;
    if (k >= Kp) return;
    float v = (k < K) ? W[(long)k * N + n] : 0.0f;
    ushort_t h, l; splitf(v, h, l);
    Whi[(long)n * Kp + k] = h;
    Wlo[(long)n * Kp + k] = l;
}

// ---------------------------------------------------------------------------
// f16x3 (scaled-lo) MFMA GEMM + bias + ELU.  C = elu(A @ W + b).
// BM=64, BN=128, BK=32, 256 thr (4 waves; wave w owns rows 0..63 x cols
// [w*32, w*32+32)).  A: LDS double-buffer (DMA or reg-staged).  B: direct
// per-lane global_load_dwordx4 from L2, REGISTER double-buffered.
// LDS (uints), per buffer 2048:
//   Ahi [0,1024): k-quad q at q*256 + row*4    (64 rows x 16B)
//   Alo [1024,2048)
// MFMA mappings (m89/m120-verified): A[m=lane&15][k=quad*8+j],
// B[k=quad*8+j][n=lane&15], C col=lane&15 row=quad*4+reg.
// ---------------------------------------------------------------------------
template<int CONCAT>
__global__ __launch_bounds__(256, 3)
void gemm_f16x3_kernel(const void* A0v, const void* A1v,
                       const ushort_t* __restrict__ Bhi, const ushort_t* __restrict__ Blo,
                       const float* __restrict__ bias,
                       ushort_t* __restrict__ Chi, ushort_t* __restrict__ Clo,
                       int Nw, int Kp, int Kvalid)
{
    __shared__ uint lds[4096];            // 2 buffers x 2048 uints (2 x 8 KB, A only)
    const int tid = threadIdx.x;
    const int w = tid >> 6, l = tid & 63;
    const int quad = l >> 4, lr = l & 15;
    const long rowBase = (long)blockIdx.x * 64;
    const int colBase = blockIdx.y * 128;
    const int nQ = w * 32;

    floatx4 accH[4][2], accX[4][2];
#pragma unroll
    for (int i = 0; i < 4; ++i)
#pragma unroll
        for (int j = 0; j < 2; ++j) { accH[i][j] = (floatx4)(0.0f); accX[i][j] = (floatx4)(0.0f); }

    // ---- B fragment base pointers (per lane, direct L2) ----
    const long nIdx0 = colBase + nQ + lr;           // jn = 0 column
    const ushort_t* pF0h = Bhi + nIdx0 * Kp + quad * 8;
    const ushort_t* pF1h = pF0h + 16 * Kp;          // jn = 1 column (+16 rows of W^T)
    const ushort_t* pF0l = Blo + nIdx0 * Kp + quad * 8;
    const ushort_t* pF1l = pF0l + 16 * Kp;

    uint4 bch0, bch1, bcl0, bcl1;                   // CURRENT-tile B (named)
    uint4 bnh0, bnh1, bnl0, bnl1;                   // NEXT-tile B (named)
    auto loadBcur = [&](int k0) {
        bch0 = *(const uint4*)(pF0h + k0);
        bch1 = *(const uint4*)(pF1h + k0);
        bcl0 = *(const uint4*)(pF0l + k0);
        bcl1 = *(const uint4*)(pF1l + k0);
    };
    auto loadBnext = [&](int k0) {
        bnh0 = *(const uint4*)(pF0h + k0);
        bnh1 = *(const uint4*)(pF1h + k0);
        bnl0 = *(const uint4*)(pF0l + k0);
        bnl1 = *(const uint4*)(pF1l + k0);
    };
    auto promoteB = [&]() {
        bch0 = bnh0; bch1 = bnh1; bcl0 = bnl0; bcl1 = bnl1;
    };

    // ---- A staging, DMA path (CONCAT==0): A already f16 hi/lo, [M,Kp] ----
    const ushort_t* pAh = (const ushort_t*)A0v + (rowBase + l) * Kp + w * 8;
    const ushort_t* pAl = (const ushort_t*)A1v + (rowBase + l) * Kp + w * 8;
    auto stageA0 = [&](int buf, int k0) {
        uint* d = &lds[buf * 2048 + w * 256];
        gload_lds16(pAh + k0, d);
        gload_lds16(pAl + k0, d + 1024);
    };

    // ---- A staging, fp32-concat path (CONCAT!=0): load->regs, convert,
    //      ds_write (all compiler-scoreboarded; __syncthreads publishes). ----
    const float* A1p = (const float*)A0v;
    const float* A2p = (const float*)A1v;
    const long grow = rowBase + l;

    auto aload = [&](float* v, int k0) {
        const int kk = k0 + w * 8;                  // wave-uniform
        if (kk >= CONCAT && kk + 8 <= Kvalid) {
            const float* p = A2p + grow * COND_D + (kk - CONCAT);
            *(float4*)&v[0] = *(const float4*)p;
            *(float4*)&v[4] = *(const float4*)(p + 4);
        } else if (kk + 8 <= CONCAT) {
            const float* p = A1p + grow * CONCAT + kk;
            *(float4*)&v[0] = *(const float4*)p;
            *(float4*)&v[4] = *(const float4*)(p + 4);
        } else {
#pragma unroll
            for (int i = 0; i < 8; ++i) {
                int k = kk + i;
                v[i] = (k < CONCAT) ? A1p[grow * CONCAT + k]
                     : (k < Kvalid) ? A2p[grow * COND_D + (k - CONCAT)] : 0.0f;
            }
        }
    };
    auto awrite = [&](int buf, const float* v) {
        uint hh[4], ll[4];
#pragma unroll
        for (int i = 0; i < 4; ++i) {
            ushort_t h0, l0, h1, l1;
            splitf(v[2 * i], h0, l0);
            splitf(v[2 * i + 1], h1, l1);
            hh[i] = (uint)h0 | ((uint)h1 << 16);
            ll[i] = (uint)l0 | ((uint)l1 << 16);
        }
        *(uint4*)&lds[buf * 2048 + w * 256 + l * 4]        = *(uint4*)hh;
        *(uint4*)&lds[buf * 2048 + 1024 + w * 256 + l * 4] = *(uint4*)ll;
    };

    // ---- compute: A from LDS, B from current regs ----
    auto compute = [&](int buf) {
        const int base = buf * 2048;
        half8 bh0 = __builtin_bit_cast(half8, bch0);
        half8 bh1 = __builtin_bit_cast(half8, bch1);
        half8 bl0 = __builtin_bit_cast(half8, bcl0);
        half8 bl1 = __builtin_bit_cast(half8, bcl1);
#pragma unroll
        for (int im = 0; im < 4; ++im) {
            int aoff = base + quad * 256 + (im * 16 + lr) * 4;
            half8 ah = __builtin_bit_cast(half8, *(uint4*)&lds[aoff]);
            half8 al = __builtin_bit_cast(half8, *(uint4*)&lds[aoff + 1024]);
            accH[im][0] = __builtin_amdgcn_mfma_f32_16x16x32_f16(ah, bh0, accH[im][0], 0, 0, 0);
            accX[im][0] = __builtin_amdgcn_mfma_f32_16x16x32_f16(ah, bl0, accX[im][0], 0, 0, 0);
            accX[im][0] = __builtin_amdgcn_mfma_f32_16x16x32_f16(al, bh0, accX[im][0], 0, 0, 0);
            accH[im][1] = __builtin_amdgcn_mfma_f32_16x16x32_f16(ah, bh1, accH[im][1], 0, 0, 0);
            accX[im][1] = __builtin_amdgcn_mfma_f32_16x16x32_f16(ah, bl1, accX[im][1], 0, 0, 0);
            accX[im][1] = __builtin_amdgcn_mfma_f32_16x16x32_f16(al, bh1, accX[im][1], 0, 0, 0);
        }
    };

    const int kTiles = Kp / 32;
    int cur = 0;
    float v[8];

    // ---- prologue: tile 0 -> buffer 0 / current B regs ----
    if constexpr (CONCAT == 0) {
        stageA0(0, 0);                      // A0 DMA
        loadBcur(0);                        // B0 regs
        __syncthreads();                    // drains DMA + publishes buf0
    } else {
        aload(v, 0);
        loadBcur(0);
        awrite(0, v);                       // compiler waits for aload regs
        __syncthreads();                    // publishes buf0 A
    }

    // ---- main loop: ALL next-tile loads issued BEFORE compute ----
    for (int t = 0; t < kTiles; ++t) {
        const bool hasNext = (t + 1 < kTiles);
        const int k0n = (t + 1) * 32;
        if constexpr (CONCAT == 0) {
            if (hasNext) {
                stageA0(cur ^ 1, k0n);      // A[t+1] DMA in flight during compute
                loadBnext(k0n);             // B[t+1] -> separate regs, in flight
            }
            compute(cur);                   // no waits: reads cur A (LDS) + cur B regs
        } else {
            if (hasNext) {
                aload(v, k0n);              // A[t+1] fp32 -> regs, in flight
                loadBnext(k0n);             // B[t+1] in flight
            }
            compute(cur);
            if (hasNext) awrite(cur ^ 1, v);  // waits aload only (landed under compute)
        }
        __syncthreads();                    // vmcnt drain finds loads already landed
        if (hasNext) promoteB();            // reg moves (cheap)
        cur ^= 1;
    }

    // ---- epilogue: combine, bias, ELU, hi/lo split store ----
    float bv[2];
#pragma unroll
    for (int jn = 0; jn < 2; ++jn) bv[jn] = bias[colBase + nQ + jn * 16 + lr];
#pragma unroll
    for (int im = 0; im < 4; ++im) {
#pragma unroll
        for (int jn = 0; jn < 2; ++jn) {
            int n = colBase + nQ + jn * 16 + lr;
#pragma unroll
            for (int rr = 0; rr < 4; ++rr) {
                long m = rowBase + im * 16 + quad * 4 + rr;
                float x = accH[im][jn][rr] + accX[im][jn][rr] * INV_LO_SCALE + bv[jn];
                x = x > 0.0f ? x : (expf(x) - 1.0f);
                ushort_t h, lo; splitf(x, h, lo);
                long idx = m * Nw + n;
                Chi[idx] = h;
                Clo[idx] = lo;
            }
        }
    }
}

// ---------------------------------------------------------------------------
// K3: z = h2@W3+b3 (fp32, h2 = hi + lo*2^-12), normalize, argmax,
// quantized -> d_out, q-latent partial, counts, distT (transposed) write.
// ---------------------------------------------------------------------------
__global__ __launch_bounds__(256)
void quantize_kernel(const ushort_t* __restrict__ h2hi, const ushort_t* __restrict__ h2lo,
                     const float* __restrict__ W3,
                     const float* __restrict__ b3, const float* __restrict__ emb,
                     float* __restrict__ distT, float* __restrict__ outQ,
                     float* __restrict__ outIdx, int* __restrict__ counts,
                     float* __restrict__ qsum)
{
    __shared__ float h2t[16 * 260];
    __shared__ float w3t[16 * 260];
    __shared__ float nwt[256 * 20];
    __shared__ float zt[16 * 17];
    __shared__ float dt[16 * 257];
    __shared__ int   lcnt[256];
    __shared__ float swred[4];

    int t = threadIdx.x;
    long rowBase = (long)blockIdx.x * 16;

    for (int it = 0; it < 16; ++it) {
        long idx = (rowBase + it) * 256 + t;
        h2t[it * 260 + t] = f16pair(h2hi[idx], h2lo[idx]);
    }
    for (int it = 0; it < 16; ++it) {
        int flat = it * 256 + t;
        int j = flat >> 4, c = flat & 15;
        w3t[c * 260 + j] = W3[flat];
    }
    {
        float e0[16]; float ss = 0.f;
#pragma unroll
        for (int i = 0; i < 16; ++i) { e0[i] = emb[t * 16 + i]; ss += e0[i] * e0[i]; }
        float inv = 1.0f / fmaxf(sqrtf(ss), 1e-12f);
#pragma unroll
        for (int i = 0; i < 16; ++i) nwt[t * 20 + i] = e0[i] * inv;
    }
    lcnt[t] = 0;
    __syncthreads();

    int r = t >> 4, c = t & 15;
    float zacc = b3[c];
    for (int j4 = 0; j4 < 64; ++j4) {
        float4 h = *(const float4*)&h2t[r * 260 + j4 * 4];
        float4 w = *(const float4*)&w3t[c * 260 + j4 * 4];
        zacc += h.x * w.x + h.y * w.y + h.z * w.z + h.w * w.w;
    }
    float ss = zacc * zacc;
#pragma unroll
    for (int m = 1; m < 16; m <<= 1) ss += __shfl_xor(ss, m, 64);
    zt[r * 17 + c] = zacc / fmaxf(sqrtf(ss), 1e-12f);
    __syncthreads();

    float zr[16];
#pragma unroll
    for (int e = 0; e < 16; ++e) zr[e] = zt[r * 17 + e];
    float best = -1e30f; int bidx = 0;
    for (int cc = 0; cc < 16; ++cc) {
        int col = cc * 16 + c;
        float d = 0.f;
#pragma unroll
        for (int e4 = 0; e4 < 4; ++e4) {
            float4 wv = *(const float4*)&nwt[col * 20 + e4 * 4];
            d += zr[e4 * 4 + 0] * wv.x + zr[e4 * 4 + 1] * wv.y
               + zr[e4 * 4 + 2] * wv.z + zr[e4 * 4 + 3] * wv.w;
        }
        dt[r * 257 + col] = d;
        if (d > best || (d == best && col < bidx)) { best = d; bidx = col; }
    }
#pragma unroll
    for (int m = 1; m < 16; m <<= 1) {
        float ov = __shfl_xor(best, m, 64);
        int   oi = __shfl_xor(bidx, m, 64);
        if (ov > best || (ov == best && oi < bidx)) { best = ov; bidx = oi; }
    }

    float q = emb[bidx * 16 + c];
    outQ[(rowBase + r) * 16 + c] = q;
    float df = q - zacc;
    float part = df * df;
#pragma unroll
    for (int m = 1; m < 64; m <<= 1) part += __shfl_xor(part, m, 64);
    if ((t & 63) == 0) swred[t >> 6] = part;
    if (c == 0) {
        outIdx[rowBase + r] = (float)bidx;
        atomicAdd(&lcnt[bidx], 1);
    }
    __syncthreads();
    if (t == 0) atomicAdd(qsum, swred[0] + swred[1] + swred[2] + swred[3]);
    if (lcnt[t] > 0) atomicAdd(&counts[t], lcnt[t]);

    int rr = t & 15, cg = t >> 4;
    for (int i = 0; i < 16; ++i) {
        int col = i * 16 + cg;
        distT[(long)col * NROWS + rowBase + rr] = dt[rr * 257 + col];
    }
}

// ---------------------------------------------------------------------------
// SelA: per-column histogram; median bin and top-512 threshold bin.
// ---------------------------------------------------------------------------
__global__ __launch_bounds__(1024)
void selA_kernel(const float* __restrict__ distT, int* __restrict__ stats)
{
    __shared__ int hist[NB];
    __shared__ int part[1024];
    int t = threadIdx.x, c = blockIdx.x;
    for (int i = t; i < NB; i += 1024) hist[i] = 0;
    __syncthreads();
    const float* col = distT + (long)c * NROWS;
    for (int i = t; i < NROWS; i += 1024) {
        float v = col[i];
        int b = (int)((v + 1.0f) * (NB * 0.5f));
        b = min(max(b, 0), NB - 1);
        atomicAdd(&hist[b], 1);
    }
    __syncthreads();
    const int CH = NB / 1024;
    int s = 0;
    for (int i = 0; i < CH; ++i) s += hist[t * CH + i];
    part[t] = s;
    __syncthreads();
    if (t == 0) {
        int target = NROWS / 2;
        int cum = 0; int chunk = 0;
        while (cum + part[chunk] < target) { cum += part[chunk]; ++chunk; }
        int b = chunk * CH;
        while (cum + hist[b] < target) { cum += hist[b]; ++b; }
        int medBin = b, needLow = target - cum, cntMed = hist[b];
        int cumA = 0; chunk = 1023;
        while (cumA + part[chunk] < 512) { cumA += part[chunk]; --chunk; }
        b = chunk * CH + CH - 1;
        while (cumA + hist[b] < 512) { cumA += hist[b]; --b; }
        int topBin = b, needTop = 512 - cumA, cntTop = hist[b];
        int* st = stats + c * 6;
        st[0] = medBin; st[1] = needLow; st[2] = cntMed;
        st[3] = topBin; st[4] = needTop; st[5] = cntTop;
    }
}

// ---------------------------------------------------------------------------
// SelB: re-scan column; top-512 mean and logsumexp over bottom half.
// ---------------------------------------------------------------------------
__global__ __launch_bounds__(1024)
void selB_kernel(const float* __restrict__ distT, const int* __restrict__ stats,
                 float* __restrict__ contra_sum)
{
    __shared__ float red[64];
    int t = threadIdx.x, c = blockIdx.x;
    const int* st = stats + c * 6;
    int medBin = st[0], needLow = st[1], cntMed = st[2];
    int topBin = st[3], needTop = st[4], cntTop = st[5];
    const float binw = 2.0f / NB;
    float mUp = -1.0f + (medBin + 1) * binw;
    const float INVT = 1.0f / 0.07f;
    const float* col = distT + (long)c * NROWS;
    float topS = 0.f, tbS = 0.f, lowS = 0.f, mbS = 0.f;
    for (int i = t; i < NROWS; i += 1024) {
        float v = col[i];
        int b = (int)((v + 1.0f) * (NB * 0.5f));
        b = min(max(b, 0), NB - 1);
        if (b > topBin)       topS += v;
        else if (b == topBin) tbS += v;
        if (b < medBin)       lowS += expf((v - mUp) * INVT);
        else if (b == medBin) mbS  += expf((v - mUp) * INVT);
    }
#pragma unroll
    for (int m = 1; m < 64; m <<= 1) {
        topS += __shfl_xor(topS, m, 64);
        tbS  += __shfl_xor(tbS, m, 64);
        lowS += __shfl_xor(lowS, m, 64);
        mbS  += __shfl_xor(mbS, m, 64);
    }
    if ((t & 63) == 0) {
        int wv = t >> 6;
        red[wv * 4 + 0] = topS; red[wv * 4 + 1] = tbS;
        red[wv * 4 + 2] = lowS; red[wv * 4 + 3] = mbS;
    }
    __syncthreads();
    if (t == 0) {
        float T0 = 0, T1 = 0, T2 = 0, T3 = 0;
        for (int wv = 0; wv < 16; ++wv) {
            T0 += red[wv * 4 + 0]; T1 += red[wv * 4 + 1];
            T2 += red[wv * 4 + 2]; T3 += red[wv * 4 + 3];
        }
        float dis_pos = (T0 + needTop * (T1 / cntTop)) * (1.0f / 512.0f);
        float S = T2 + needLow * (T3 / cntMed);
        float colContra = log1pf(S * expf((mUp - dis_pos) * INVT));
        atomicAdd(contra_sum, colContra);
    }
}

// ---------------------------------------------------------------------------
// D3: reconstructed = d2 @ dec_w3 + b (d2 = hi + lo*2^-12), + recon loss.
// ---------------------------------------------------------------------------
__global__ __launch_bounds__(256)
void dec3_kernel(const ushort_t* __restrict__ d2hi, const ushort_t* __restrict__ d2lo,
                 const float* __restrict__ W,
                 const float* __restrict__ bias, const float* __restrict__ actions,
                 float* __restrict__ rec, float* __restrict__ recon_sum)
{
    __shared__ float dtile[16 * 516];
    __shared__ float wt[512 * 12];
    __shared__ float red2[4];
    int t = threadIdx.x;
    long rowBase = (long)blockIdx.x * 16;
    for (int it = 0; it < 24; ++it) wt[it * 256 + t] = W[it * 256 + t];
    for (int it = 0; it < 32; ++it) {
        int flat = it * 256 + t;
        int r = flat >> 9, k = flat & 511;
        long idx = (rowBase + r) * 512 + k;
        dtile[r * 516 + k] = f16pair(d2hi[idx], d2lo[idx]);
    }
    __syncthreads();
    float part = 0.f;
    if (t < 192) {
        int r = t / 12, cc = t % 12;
        float acc = bias[cc];
        for (int k4 = 0; k4 < 128; ++k4) {
            float4 h = *(const float4*)&dtile[r * 516 + k4 * 4];
            acc += h.x * wt[(k4 * 4 + 0) * 12 + cc] + h.y * wt[(k4 * 4 + 1) * 12 + cc]
                 + h.z * wt[(k4 * 4 + 2) * 12 + cc] + h.w * wt[(k4 * 4 + 3) * 12 + cc];
        }
        rec[(rowBase + r) * 12 + cc] = acc;
        float df = acc - actions[(rowBase + r) * 12 + cc];
        part = df * df;
    }
#pragma unroll
    for (int m = 1; m < 64; m <<= 1) part += __shfl_xor(part, m, 64);
    if ((t & 63) == 0) red2[t >> 6] = part;
    __syncthreads();
    if (t == 0) atomicAdd(recon_sum, red2[0] + red2[1] + red2[2] + red2[3]);
}

// ---------------------------------------------------------------------------
// finalize: perplexity from counts + scalar outputs.
// ---------------------------------------------------------------------------
__global__ void finalize_kernel(const int* __restrict__ counts, float* __restrict__ outScal)
{
    __shared__ float red[4];
    int t = threadIdx.x;
    float p = counts[t] * (1.0f / NROWS);
    float term = p * logf(p + 1e-10f);
#pragma unroll
    for (int m = 1; m < 64; m <<= 1) term += __shfl_xor(term, m, 64);
    if ((t & 63) == 0) red[t >> 6] = term;
    __syncthreads();
    if (t == 0) {
        float hsum = red[0] + red[1] + red[2] + red[3];
        float qsum = outScal[0], contra = outScal[2], recon = outScal[4];
        float ql = qsum * (1.0f / (NROWS * 16.0f));
        outScal[0] = ql;
        outScal[1] = 0.25f * ql;
        outScal[2] = contra * (1.0f / 256.0f);
        outScal[3] = expf(-hsum);
        outScal[4] = recon * (1.0f / (NROWS * 12.0f));
    }
}

extern "C" void kernel_launch(void* const* d_in, const int* in_sizes, int n_in,
                              void* d_out, int out_size, void* d_ws, size_t ws_size,
                              hipStream_t stream)
{
    const float* actions    = (const float*)d_in[0];
    const float* conditions = (const float*)d_in[1];
    const float* enc_w1 = (const float*)d_in[2];
    const float* enc_b1 = (const float*)d_in[3];
    const float* enc_w2 = (const float*)d_in[4];
    const float* enc_b2 = (const float*)d_in[5];
    const float* enc_w3 = (const float*)d_in[6];
    const float* enc_b3 = (const float*)d_in[7];
    const float* dec_w1 = (const float*)d_in[8];
    const float* dec_b1 = (const float*)d_in[9];
    const float* dec_w2 = (const float*)d_in[10];
    const float* dec_b2 = (const float*)d_in[11];
    const float* dec_w3 = (const float*)d_in[12];
    const float* dec_b3 = (const float*)d_in[13];
    const float* emb    = (const float*)d_in[14];

    float* out     = (float*)d_out;
    float* outRec  = out;
    float* outQ    = out + (long)NROWS * 12;
    float* outIdx  = out + (long)NROWS * 28;
    float* outScal = out + (long)NROWS * 29;

    // converted weights live in the (dead-until-dec3) outRec region
    ushort_t* wb    = (ushort_t*)d_out;
    ushort_t* w1hi  = wb;            ushort_t* w1lo  = wb + 147456;
    ushort_t* w2hi  = wb + 294912;   ushort_t* w2lo  = wb + 425984;
    ushort_t* wd1hi = wb + 557056;   ushort_t* wd1lo = wb + 630784;
    ushort_t* wd2hi = wb + 704512;   ushort_t* wd2lo = wb + 835584;

    float* ws = (float*)d_ws;
    int* counts = (int*)ws;
    int* stats  = (int*)(ws + 256);
    ushort_t* h2hi = (ushort_t*)(ws + 1792);
    ushort_t* h2lo = (ushort_t*)(ws + 16779008);
    ushort_t* d1hi = h2hi;
    ushort_t* d1lo = h2lo;
    float*    P1   = ws + 33556224;
    ushort_t* h1hi = (ushort_t*)P1;
    ushort_t* h1lo = (ushort_t*)(ws + 67110656);
    float*    distT = P1;
    ushort_t* d2hi = h1hi;
    ushort_t* d2lo = h1lo;

    hipLaunchKernelGGL(init_kernel, dim3(1), dim3(256), 0, stream, counts, outScal);
    hipLaunchKernelGGL(convw_kernel, dim3(512, 2), dim3(256), 0, stream, enc_w1, w1hi, w1lo, 268, 512, 288);
    hipLaunchKernelGGL(convw_kernel, dim3(256, 2), dim3(256), 0, stream, enc_w2, w2hi, w2lo, 512, 256, 512);
    hipLaunchKernelGGL(convw_kernel, dim3(256, 2), dim3(256), 0, stream, dec_w1, wd1hi, wd1lo, 272, 256, 288);
    hipLaunchKernelGGL(convw_kernel, dim3(512, 1), dim3(256), 0, stream, dec_w2, wd2hi, wd2lo, 256, 512, 256);
    // E1: h1 = elu(concat(actions,conditions) @ W1 + b1)
    hipLaunchKernelGGL((gemm_f16x3_kernel<ACT_D>), dim3(2048, 4), dim3(256), 0, stream,
                       (const void*)actions, (const void*)conditions, w1hi, w1lo, enc_b1,
                       h1hi, h1lo, H1D, 288, 268);
    // E2: h2 = elu(h1 @ W2 + b2)
    hipLaunchKernelGGL((gemm_f16x3_kernel<0>), dim3(2048, 2), dim3(256), 0, stream,
                       (const void*)h1hi, (const void*)h1lo, w2hi, w2lo, enc_b2,
                       h2hi, h2lo, H2D, 512, 512);
    // K3: z, normalize, argmax, quantized, counts, q-latent, distT
    hipLaunchKernelGGL(quantize_kernel, dim3(8192), dim3(256), 0, stream,
                       h2hi, h2lo, enc_w3, enc_b3, emb, distT, outQ, outIdx, counts, &outScal[0]);
    hipLaunchKernelGGL(selA_kernel, dim3(256), dim3(1024), 0, stream, distT, stats);
    hipLaunchKernelGGL(selB_kernel, dim3(256), dim3(1024), 0, stream, distT, stats, &outScal[2]);
    // D1: d1 = elu(concat(quantized,conditions) @ Wd1 + b1)
    hipLaunchKernelGGL((gemm_f16x3_kernel<EDIM>), dim3(2048, 2), dim3(256), 0, stream,
                       (const void*)outQ, (const void*)conditions, wd1hi, wd1lo, dec_b1,
                       d1hi, d1lo, H2D, 288, 272);
    // D2: d2 = elu(d1 @ Wd2 + b2)
    hipLaunchKernelGGL((gemm_f16x3_kernel<0>), dim3(2048, 4), dim3(256), 0, stream,
                       (const void*)d1hi, (const void*)d1lo, wd2hi, wd2lo, dec_b2,
                       d2hi, d2lo, H1D, 256, 256);
    // D3: reconstructed + loss
    hipLaunchKernelGGL(dec3_kernel, dim3(8192), dim3(256), 0, stream,
                       d2hi, d2lo, dec_w3, dec_b3, actions, outRec, &outScal[4]);
    hipLaunchKernelGGL(finalize_kernel, dim3(1), dim3(256), 0, stream, counts, outScal);
}